// Round 10
// baseline (240.969 us; speedup 1.0000x reference)
//
#include <hip/hip_runtime.h>

namespace {

typedef float  f32x4  __attribute__((ext_vector_type(4)));
typedef float  f32x16 __attribute__((ext_vector_type(16)));
typedef short  bf16x8 __attribute__((ext_vector_type(8)));
typedef int    i32x4  __attribute__((ext_vector_type(4)));
typedef unsigned int u32;

constexpr int kRows  = 524288;
constexpr int kCont  = 64;
constexpr int kNCate = 16;
constexpr int kVocab = 1000;
constexpr int kEm    = 8;
constexpr int kRH    = 32;
constexpr int kPH    = 16;

constexpr int    kNFrag = 48;
constexpr size_t kOffEH = (size_t)kNFrag * 1024;    // 49152
constexpr size_t kOffEL = kOffEH + 256000;

__device__ inline u32 rne_hi(float x) {
    u32 u = __float_as_uint(x);
    return ((u + 0x7fffu + ((u >> 16) & 1u)) >> 16) & 0xffffu;
}
__device__ inline float hi_f32(u32 h) { return __uint_as_float(h << 16); }
// pack two floats as bf16 pair: a -> low16, b -> high16 (verified R6/R9 math)
__device__ inline u32 pack2(float a, float b) {
    return rne_hi(a) | (rne_hi(b) << 16);
}

union FragU { u32 w[4]; bf16x8 v; uint4 u4; };

__device__ inline f32x16 mfma16(bf16x8 a, bf16x8 b, f32x16 c) {
    return __builtin_amdgcn_mfma_f32_32x32x16_bf16(a, b, c, 0, 0, 0);
}
__device__ inline f32x16 zero16() {
    f32x16 z;
#pragma unroll
    for (int i = 0; i < 16; ++i) z[i] = 0.f;
    return z;
}

// ---------------------------------------------------------------------------
// Pre-kernel 1 (unchanged since R6 — hardware-verified frag convention).
// ---------------------------------------------------------------------------
__global__ __launch_bounds__(256) void build_wfrags(
    const float* __restrict__ W1, const float* __restrict__ W2,
    const float* __restrict__ W3, const float* __restrict__ HW1,
    ushort* __restrict__ WF)
{
    int gid = blockIdx.x * blockDim.x + threadIdx.x;
    if (gid >= kNFrag * 64) return;
    const int q = gid >> 6, l = gid & 63;
    const int lc = l & 31, g = l >> 5;

    const float* src; int k0, col, ldn, p;
    if (q < 12)      { src = W1; k0 = 16*q + 8*g;      col = lc; ldn = 32; p = 0; }
    else if (q < 24) { src = W1; k0 = 16*(q-12) + 8*g; col = lc; ldn = 32; p = 1; }
    else if (q < 28) { int u2 = q-24; src = W2; k0 = 16*(u2>>1) + 8*g; col = lc; ldn = 32; p = u2&1; }
    else if (q < 32) { int u2 = q-28; src = W3; k0 = 16*(u2>>1) + 8*g; col = lc; ldn = 32; p = u2&1; }
    else {
        int u2 = q-32; int n = u2>>2; int f = (u2>>1)&1; p = u2&1;
        int c128 = n*32 + lc; int head = c128 >> 4, ph = c128 & 15;
        src = HW1 + (size_t)head * kRH * kPH + ph;
        k0 = 16*f + 8*g; col = 0; ldn = kPH;
    }

    u32 hv[8];
#pragma unroll
    for (int j = 0; j < 8; ++j) {
        float w = src[(size_t)(k0 + j) * ldn + col];
        u32 h = rne_hi(w);
        hv[j] = (p == 0) ? h : rne_hi(w - hi_f32(h));
    }
    FragU fu;
#pragma unroll
    for (int w = 0; w < 4; ++w) fu.w[w] = hv[2*w] | (hv[2*w+1] << 16);
    ((uint4*)WF)[q * 64 + l] = fu.u4;
}

// ---------------------------------------------------------------------------
// Pre-kernel 2 (unchanged): emb -> bf16 hi/lo tables, 16B rows.
// ---------------------------------------------------------------------------
__global__ __launch_bounds__(256) void build_embsplit(
    const float* __restrict__ emb, ushort* __restrict__ eh, ushort* __restrict__ el)
{
    int r = blockIdx.x * blockDim.x + threadIdx.x;
    if (r >= kNCate * kVocab) return;
    const float* e = emb + (size_t)r * kEm;
    FragU H, L;
#pragma unroll
    for (int w = 0; w < 4; ++w) {
        float a = e[2*w], b = e[2*w+1];
        u32 ha = rne_hi(a), hb_ = rne_hi(b);
        u32 la = rne_hi(a - hi_f32(ha)), lb = rne_hi(b - hi_f32(hb_));
        H.w[w] = ha | (hb_ << 16);
        L.w[w] = la | (lb << 16);
    }
    ((uint4*)eh)[r] = H.u4;
    ((uint4*)el)[r] = L.u4;
}

// ---------------------------------------------------------------------------
// Transition (unchanged from R9, verified): 16 per-lane f32 -> hi/lo B-frags.
// ---------------------------------------------------------------------------
__device__ inline void transition(const float* v, int g, FragU* H, FragU* L) {
    u32 hw[8], lw[8];
#pragma unroll
    for (int p = 0; p < 8; ++p) {
        float v0 = v[2*p], v1 = v[2*p+1];
        u32 h0 = rne_hi(v0), h1 = rne_hi(v1);
        hw[p] = h0 | (h1 << 16);
        lw[p] = pack2(v0 - hi_f32(h0), v1 - hi_f32(h1));
    }
#pragma unroll
    for (int f2 = 0; f2 < 2; ++f2) {
        u32 hp[4], lp[4];
#pragma unroll
        for (int p = 0; p < 4; ++p) {
            hp[p] = (u32)__shfl_xor((int)hw[4*f2 + p], 32);
            lp[p] = (u32)__shfl_xor((int)lw[4*f2 + p], 32);
        }
        H[f2].w[0] = g ? hp[2] : hw[4*f2+0];
        H[f2].w[1] = g ? hp[3] : hw[4*f2+1];
        H[f2].w[2] = g ? hw[4*f2+2] : hp[0];
        H[f2].w[3] = g ? hw[4*f2+3] : hp[1];
        L[f2].w[0] = g ? lp[2] : lw[4*f2+0];
        L[f2].w[1] = g ? lp[3] : lw[4*f2+1];
        L[f2].w[2] = g ? lw[4*f2+2] : lp[0];
        L[f2].w[3] = g ? lw[4*f2+3] : lp[1];
    }
}

// ---------------------------------------------------------------------------
// Main kernel (R10): 512 threads = 8 waves/block, 1 M-tile (32 samples)/wave.
// LDS only holds frags q0..31 (32 KB) + small tables -> 34.2 KB/block ->
// 3 blocks/CU = 24 waves/CU (was 12). HW1 hi+lo both read from global (L1).
// ---------------------------------------------------------------------------
__global__ __launch_bounds__(512, 6) void fused_main(
    const float* __restrict__ xc, const int* __restrict__ xcate,
    const int* __restrict__ tptr,
    const ushort* __restrict__ WF,
    const ushort* __restrict__ embh, const ushort* __restrict__ embl,
    const float* __restrict__ b1, const float* __restrict__ b2,
    const float* __restrict__ b3, const float* __restrict__ Hb1,
    const float* __restrict__ HW2, const float* __restrict__ Hb2,
    float* __restrict__ out)
{
    __shared__ __align__(16) uint4 sW4[32 * 64];   // 32 KB: frags q0..31
    __shared__ __align__(16) float sB[360];        // b1,b2,b3 | Hb1 | HW2 | Hb2

    const int tid = threadIdx.x;
    const uint4* wf4 = (const uint4*)WF;

#pragma unroll
    for (int it = 0; it < 4; ++it) {
        const int i = tid + 512 * it;              // 0..2047 = q*64+l directly
        sW4[i] = wf4[i];
    }
    for (int i = tid; i < 360; i += 512) {
        float v;
        if      (i < 32)  v = b1[i];
        else if (i < 64)  v = b2[i - 32];
        else if (i < 96)  v = b3[i - 64];
        else if (i < 224) v = Hb1[i - 96];
        else if (i < 352) v = HW2[i - 224];
        else              v = Hb2[i - 352];
        sB[i] = v;
    }
    __syncthreads();

    const int wv = tid >> 6, l = tid & 63;
    const int lc = l & 31, g = l >> 5;
    const int tb = blockIdx.x * 256 + wv * 32;
    const int arow = tb + lc;                      // this lane's sample

    // ---- issue all global loads up front ----
    i32x4 cq[4];
    {
        const i32x4* cr4 = (const i32x4*)(xcate + (size_t)arow * kNCate);
#pragma unroll
        for (int q = 0; q < 4; ++q) cq[q] = cr4[q];
    }
    f32x4 xa[8];
    {
        const f32x4* xr4 = (const f32x4*)(xc + (size_t)arow * kCont);
#pragma unroll
        for (int f = 0; f < 4; ++f) { xa[2*f] = xr4[4*f + 2*g]; xa[2*f+1] = xr4[4*f + 2*g + 1]; }
    }
    uint4 ehv[8], elv[8];
#pragma unroll
    for (int i = 0; i < 8; ++i) {
        const int c   = 2*i + g;
        const int idx = cq[i >> 1][2*(i & 1) + g];
        const size_t ro = (size_t)(c * kVocab + idx);
        ehv[i] = ((const uint4*)embh)[ro];
        elv[i] = ((const uint4*)embl)[ro];
    }
    const int t_lane = tptr[arow];

    // ---- layer 1: acc = Wh@Xh + Wl@Xh + Wh@Xl over 12 k-frags ----
    f32x16 acca = zero16(), accb = zero16();
#pragma unroll
    for (int f = 0; f < 4; ++f) {                  // x_cont frags, runtime split
        FragU H, L;
#pragma unroll
        for (int w = 0; w < 4; ++w) {
            const f32x4& va = (w < 2) ? xa[2*f] : xa[2*f+1];
            const float v0 = va[2*(w & 1)], v1 = va[2*(w & 1) + 1];
            u32 h0 = rne_hi(v0), h1 = rne_hi(v1);
            H.w[w] = h0 | (h1 << 16);
            L.w[w] = pack2(v0 - hi_f32(h0), v1 - hi_f32(h1));
        }
        FragU WH, WL;
        WH.u4 = sW4[f * 64 + l];
        WL.u4 = sW4[(12 + f) * 64 + l];
        f32x16& acc = (f & 1) ? accb : acca;
        acc = mfma16(WH.v, H.v, acc);
        acc = mfma16(WL.v, H.v, acc);
        acc = mfma16(WH.v, L.v, acc);
    }
#pragma unroll
    for (int i = 0; i < 8; ++i) {                  // emb frags, pre-split
        const int f = 4 + i;
        FragU BH, BL, WH, WL;
        BH.u4 = ehv[i]; BL.u4 = elv[i];
        WH.u4 = sW4[f * 64 + l];
        WL.u4 = sW4[(12 + f) * 64 + l];
        f32x16& acc = (f & 1) ? accb : acca;
        acc = mfma16(WH.v, BH.v, acc);
        acc = mfma16(WL.v, BH.v, acc);
        acc = mfma16(WH.v, BL.v, acc);
    }

    // bias1 + relu  (b[row(r,g)] = quad at 8p+4g)
    float v1v[16];
    {
#pragma unroll
        for (int p = 0; p < 4; ++p) {
            f32x4 bq = *(const f32x4*)&sB[0 + 8*p + 4*g];
#pragma unroll
            for (int m = 0; m < 4; ++m)
                v1v[4*p + m] = fmaxf(acca[4*p + m] + accb[4*p + m] + bq[m], 0.f);
        }
    }
    FragU a2h[2], a2l[2];
    transition(v1v, g, a2h, a2l);

    // ---- layer 2 ----
    f32x16 acc2 = zero16();
#pragma unroll
    for (int f2 = 0; f2 < 2; ++f2) {
        FragU WH, WL;
        WH.u4 = sW4[(24 + 2*f2) * 64 + l];
        WL.u4 = sW4[(25 + 2*f2) * 64 + l];
        acc2 = mfma16(WH.v, a2h[f2].v, acc2);
        acc2 = mfma16(WL.v, a2h[f2].v, acc2);
        acc2 = mfma16(WH.v, a2l[f2].v, acc2);
    }
    float v2v[16];
    {
#pragma unroll
        for (int p = 0; p < 4; ++p) {
            f32x4 bq = *(const f32x4*)&sB[32 + 8*p + 4*g];
#pragma unroll
            for (int m = 0; m < 4; ++m)
                v2v[4*p + m] = fmaxf(acc2[4*p + m] + bq[m], 0.f);
        }
    }
    FragU a3h[2], a3l[2];
    transition(v2v, g, a3h, a3l);

    // ---- layer 3 (no relu) ----
    f32x16 acc3 = zero16();
#pragma unroll
    for (int f2 = 0; f2 < 2; ++f2) {
        FragU WH, WL;
        WH.u4 = sW4[(28 + 2*f2) * 64 + l];
        WL.u4 = sW4[(29 + 2*f2) * 64 + l];
        acc3 = mfma16(WH.v, a3h[f2].v, acc3);
        acc3 = mfma16(WL.v, a3h[f2].v, acc3);
        acc3 = mfma16(WH.v, a3l[f2].v, acc3);
    }
    float v3v[16];
    {
#pragma unroll
        for (int p = 0; p < 4; ++p) {
            f32x4 bq = *(const f32x4*)&sB[64 + 8*p + 4*g];
#pragma unroll
            for (int m = 0; m < 4; ++m)
                v3v[4*p + m] = acc3[4*p + m] + bq[m];
        }
    }
    FragU a4h[2], a4l[2];
    transition(v3v, g, a4h, a4l);

    // ---- heads: 4 A-tiles (2 heads each); HW1 hi+lo from global (L1) ----
    const f32x4 hb1q0 = *(const f32x4*)&sB[96  + t_lane*16 + 4*g];
    const f32x4 hb1q1 = *(const f32x4*)&sB[96  + t_lane*16 + 8 + 4*g];
    const f32x4 hw2q0 = *(const f32x4*)&sB[224 + t_lane*16 + 4*g];
    const f32x4 hw2q1 = *(const f32x4*)&sB[224 + t_lane*16 + 8 + 4*g];

    float ys = 0.f;
#pragma unroll
    for (int n = 0; n < 4; ++n) {
        f32x16 hacc = zero16();
#pragma unroll
        for (int f2 = 0; f2 < 2; ++f2) {
            FragU WH, WL;
            WH.u4 = wf4[(32 + 4*n + 2*f2) * 64 + l];      // HW1-hi (global)
            WL.u4 = wf4[(33 + 4*n + 2*f2) * 64 + l];      // HW1-lo (global)
            hacc = mfma16(WH.v, a4h[f2].v, hacc);
            hacc = mfma16(WL.v, a4h[f2].v, hacc);
            hacc = mfma16(WH.v, a4l[f2].v, hacc);
        }
        const bool sel = ((t_lane >> 1) == n);
        const bool half = (t_lane & 1);
#pragma unroll
        for (int j = 0; j < 8; ++j) {
            const float bb = (j < 4) ? hb1q0[j] : hb1q1[j - 4];
            const float ww = (j < 4) ? hw2q0[j] : hw2q1[j - 4];
            const float c0 = fmaxf(hacc[j]     + bb, 0.f) * ww;
            const float c1 = fmaxf(hacc[8 + j] + bb, 0.f) * ww;
            const float pick = half ? c1 : c0;
            ys += sel ? pick : 0.f;
        }
    }

    const float ytot = ys + __shfl_xor(ys, 32);
    if (g == 0)
        out[arow] = ytot + sB[352 + t_lane];
}

} // namespace

extern "C" void kernel_launch(void* const* d_in, const int* in_sizes, int n_in,
                              void* d_out, int out_size, void* d_ws, size_t ws_size,
                              hipStream_t stream)
{
    const float* x_cont = (const float*)d_in[0];
    const int*   x_cate = (const int*)  d_in[1];
    const int*   t      = (const int*)  d_in[2];
    const float* emb    = (const float*)d_in[3];
    const float* W1     = (const float*)d_in[4];
    const float* b1     = (const float*)d_in[5];
    const float* W2     = (const float*)d_in[6];
    const float* b2     = (const float*)d_in[7];
    const float* W3     = (const float*)d_in[8];
    const float* b3     = (const float*)d_in[9];
    const float* HW1    = (const float*)d_in[10];
    const float* Hb1    = (const float*)d_in[11];
    const float* HW2    = (const float*)d_in[12];
    const float* Hb2    = (const float*)d_in[13];
    float* out = (float*)d_out;

    ushort* WF = (ushort*)d_ws;
    ushort* eh = (ushort*)((char*)d_ws + kOffEH);
    ushort* el = (ushort*)((char*)d_ws + kOffEL);

    hipLaunchKernelGGL(build_wfrags, dim3(12), dim3(256), 0, stream, W1, W2, W3, HW1, WF);
    hipLaunchKernelGGL(build_embsplit, dim3((kNCate*kVocab + 255)/256), dim3(256), 0, stream,
                       emb, eh, el);

    const int grid = kRows / 256;   // 2048 blocks, 256 rows each (8 waves x 32)
    hipLaunchKernelGGL(fused_main, dim3(grid), dim3(512), 0, stream,
                       x_cont, x_cate, t, WF, eh, el,
                       b1, b2, b3, Hb1, HW2, Hb2, out);
}

// Round 11
// 99.108 us; speedup vs baseline: 2.4314x; 2.4314x over previous
//
#include <hip/hip_runtime.h>

namespace {

typedef float  f32x4  __attribute__((ext_vector_type(4)));
typedef float  f32x16 __attribute__((ext_vector_type(16)));
typedef short  bf16x8 __attribute__((ext_vector_type(8)));
typedef int    i32x4  __attribute__((ext_vector_type(4)));
typedef unsigned int u32;

constexpr int kRows  = 524288;
constexpr int kCont  = 64;
constexpr int kNCate = 16;
constexpr int kVocab = 1000;
constexpr int kEm    = 8;
constexpr int kRH    = 32;
constexpr int kPH    = 16;

constexpr int    kNFrag = 48;
constexpr size_t kOffEH = (size_t)kNFrag * 1024;    // 49152
constexpr size_t kOffEL = kOffEH + 256000;

__device__ inline u32 rne_hi(float x) {
    u32 u = __float_as_uint(x);
    return ((u + 0x7fffu + ((u >> 16) & 1u)) >> 16) & 0xffffu;
}
__device__ inline float hi_f32(u32 h) { return __uint_as_float(h << 16); }
// pack two floats as bf16 pair: a -> low16, b -> high16 (verified R6/R9 math)
__device__ inline u32 pack2(float a, float b) {
    return rne_hi(a) | (rne_hi(b) << 16);
}

union FragU { u32 w[4]; bf16x8 v; uint4 u4; };

__device__ inline f32x16 mfma16(bf16x8 a, bf16x8 b, f32x16 c) {
    return __builtin_amdgcn_mfma_f32_32x32x16_bf16(a, b, c, 0, 0, 0);
}
__device__ inline f32x16 zero16() {
    f32x16 z;
#pragma unroll
    for (int i = 0; i < 16; ++i) z[i] = 0.f;
    return z;
}

// ---------------------------------------------------------------------------
// Pre-kernel 1 (unchanged since R6 — hardware-verified frag convention).
// ---------------------------------------------------------------------------
__global__ __launch_bounds__(256) void build_wfrags(
    const float* __restrict__ W1, const float* __restrict__ W2,
    const float* __restrict__ W3, const float* __restrict__ HW1,
    ushort* __restrict__ WF)
{
    int gid = blockIdx.x * blockDim.x + threadIdx.x;
    if (gid >= kNFrag * 64) return;
    const int q = gid >> 6, l = gid & 63;
    const int lc = l & 31, g = l >> 5;

    const float* src; int k0, col, ldn, p;
    if (q < 12)      { src = W1; k0 = 16*q + 8*g;      col = lc; ldn = 32; p = 0; }
    else if (q < 24) { src = W1; k0 = 16*(q-12) + 8*g; col = lc; ldn = 32; p = 1; }
    else if (q < 28) { int u2 = q-24; src = W2; k0 = 16*(u2>>1) + 8*g; col = lc; ldn = 32; p = u2&1; }
    else if (q < 32) { int u2 = q-28; src = W3; k0 = 16*(u2>>1) + 8*g; col = lc; ldn = 32; p = u2&1; }
    else {
        int u2 = q-32; int n = u2>>2; int f = (u2>>1)&1; p = u2&1;
        int c128 = n*32 + lc; int head = c128 >> 4, ph = c128 & 15;
        src = HW1 + (size_t)head * kRH * kPH + ph;
        k0 = 16*f + 8*g; col = 0; ldn = kPH;
    }

    u32 hv[8];
#pragma unroll
    for (int j = 0; j < 8; ++j) {
        float w = src[(size_t)(k0 + j) * ldn + col];
        u32 h = rne_hi(w);
        hv[j] = (p == 0) ? h : rne_hi(w - hi_f32(h));
    }
    FragU fu;
#pragma unroll
    for (int w = 0; w < 4; ++w) fu.w[w] = hv[2*w] | (hv[2*w+1] << 16);
    ((uint4*)WF)[q * 64 + l] = fu.u4;
}

// ---------------------------------------------------------------------------
// Pre-kernel 2 (unchanged): emb -> bf16 hi/lo tables, 16B rows.
// ---------------------------------------------------------------------------
__global__ __launch_bounds__(256) void build_embsplit(
    const float* __restrict__ emb, ushort* __restrict__ eh, ushort* __restrict__ el)
{
    int r = blockIdx.x * blockDim.x + threadIdx.x;
    if (r >= kNCate * kVocab) return;
    const float* e = emb + (size_t)r * kEm;
    FragU H, L;
#pragma unroll
    for (int w = 0; w < 4; ++w) {
        float a = e[2*w], b = e[2*w+1];
        u32 ha = rne_hi(a), hb_ = rne_hi(b);
        u32 la = rne_hi(a - hi_f32(ha)), lb = rne_hi(b - hi_f32(hb_));
        H.w[w] = ha | (hb_ << 16);
        L.w[w] = la | (lb << 16);
    }
    ((uint4*)eh)[r] = H.u4;
    ((uint4*)el)[r] = L.u4;
}

// ---------------------------------------------------------------------------
// Transition (unchanged from R9, verified): 16 per-lane f32 -> hi/lo B-frags.
// ---------------------------------------------------------------------------
__device__ inline void transition(const float* v, int g, FragU* H, FragU* L) {
    u32 hw[8], lw[8];
#pragma unroll
    for (int p = 0; p < 8; ++p) {
        float v0 = v[2*p], v1 = v[2*p+1];
        u32 h0 = rne_hi(v0), h1 = rne_hi(v1);
        hw[p] = h0 | (h1 << 16);
        lw[p] = pack2(v0 - hi_f32(h0), v1 - hi_f32(h1));
    }
#pragma unroll
    for (int f2 = 0; f2 < 2; ++f2) {
        u32 hp[4], lp[4];
#pragma unroll
        for (int p = 0; p < 4; ++p) {
            hp[p] = (u32)__shfl_xor((int)hw[4*f2 + p], 32);
            lp[p] = (u32)__shfl_xor((int)lw[4*f2 + p], 32);
        }
        H[f2].w[0] = g ? hp[2] : hw[4*f2+0];
        H[f2].w[1] = g ? hp[3] : hw[4*f2+1];
        H[f2].w[2] = g ? hw[4*f2+2] : hp[0];
        H[f2].w[3] = g ? hw[4*f2+3] : hp[1];
        L[f2].w[0] = g ? lp[2] : lw[4*f2+0];
        L[f2].w[1] = g ? lp[3] : lw[4*f2+1];
        L[f2].w[2] = g ? lw[4*f2+2] : lp[0];
        L[f2].w[3] = g ? lw[4*f2+3] : lp[1];
    }
}

// ---------------------------------------------------------------------------
// Main kernel (R11): 256 threads = 4 waves, 1 M-tile (32 samples)/wave.
// LDS holds ONLY W1 hi+lo frags (24 KB) + small tables -> ~25.5 KB/block ->
// runtime packs 6 blocks/CU = 24 waves/CU (2x R9). W2/W3/head frags read
// directly from global (24 KB working set, L1-resident, static addresses).
// NO restrictive VGPR cap (R10 lesson: cap -> scratch spill catastrophe).
// ---------------------------------------------------------------------------
__global__ __launch_bounds__(256, 4) void fused_main(
    const float* __restrict__ xc, const int* __restrict__ xcate,
    const int* __restrict__ tptr,
    const ushort* __restrict__ WF,
    const ushort* __restrict__ embh, const ushort* __restrict__ embl,
    const float* __restrict__ b1, const float* __restrict__ b2,
    const float* __restrict__ b3, const float* __restrict__ Hb1,
    const float* __restrict__ HW2, const float* __restrict__ Hb2,
    float* __restrict__ out)
{
    __shared__ __align__(16) uint4 sW4[24 * 64];   // 24 KB: W1 frags q0..23
    __shared__ __align__(16) float sB[360];        // b1,b2,b3 | Hb1 | HW2 | Hb2

    const int tid = threadIdx.x;
    const uint4* wf4 = (const uint4*)WF;

#pragma unroll
    for (int it = 0; it < 6; ++it) {
        const int i = tid + 256 * it;              // 0..1535 = q*64+l for q<24
        sW4[i] = wf4[i];
    }
    for (int i = tid; i < 360; i += 256) {
        float v;
        if      (i < 32)  v = b1[i];
        else if (i < 64)  v = b2[i - 32];
        else if (i < 96)  v = b3[i - 64];
        else if (i < 224) v = Hb1[i - 96];
        else if (i < 352) v = HW2[i - 224];
        else              v = Hb2[i - 352];
        sB[i] = v;
    }
    __syncthreads();

    const int wv = tid >> 6, l = tid & 63;
    const int lc = l & 31, g = l >> 5;
    const int tb = blockIdx.x * 128 + wv * 32;
    const int arow = tb + lc;                      // this lane's sample

    // ---- issue all global loads up front ----
    i32x4 cq[4];
    {
        const i32x4* cr4 = (const i32x4*)(xcate + (size_t)arow * kNCate);
#pragma unroll
        for (int q = 0; q < 4; ++q) cq[q] = cr4[q];
    }
    f32x4 xa[8];
    {
        const f32x4* xr4 = (const f32x4*)(xc + (size_t)arow * kCont);
#pragma unroll
        for (int f = 0; f < 4; ++f) { xa[2*f] = xr4[4*f + 2*g]; xa[2*f+1] = xr4[4*f + 2*g + 1]; }
    }
    uint4 ehv[8], elv[8];
#pragma unroll
    for (int i = 0; i < 8; ++i) {
        const int c   = 2*i + g;
        const int idx = cq[i >> 1][2*(i & 1) + g];
        const size_t ro = (size_t)(c * kVocab + idx);
        ehv[i] = ((const uint4*)embh)[ro];
        elv[i] = ((const uint4*)embl)[ro];
    }
    const int t_lane = tptr[arow];

    // ---- layer 1: acc = Wh@Xh + Wl@Xh + Wh@Xl over 12 k-frags ----
    f32x16 acca = zero16(), accb = zero16();
#pragma unroll
    for (int f = 0; f < 4; ++f) {                  // x_cont frags, runtime split
        FragU H, L;
#pragma unroll
        for (int w = 0; w < 4; ++w) {
            const f32x4& va = (w < 2) ? xa[2*f] : xa[2*f+1];
            const float v0 = va[2*(w & 1)], v1 = va[2*(w & 1) + 1];
            u32 h0 = rne_hi(v0), h1 = rne_hi(v1);
            H.w[w] = h0 | (h1 << 16);
            L.w[w] = pack2(v0 - hi_f32(h0), v1 - hi_f32(h1));
        }
        FragU WH, WL;
        WH.u4 = sW4[f * 64 + l];
        WL.u4 = sW4[(12 + f) * 64 + l];
        f32x16& acc = (f & 1) ? accb : acca;
        acc = mfma16(WH.v, H.v, acc);
        acc = mfma16(WL.v, H.v, acc);
        acc = mfma16(WH.v, L.v, acc);
    }
#pragma unroll
    for (int i = 0; i < 8; ++i) {                  // emb frags, pre-split
        const int f = 4 + i;
        FragU BH, BL, WH, WL;
        BH.u4 = ehv[i]; BL.u4 = elv[i];
        WH.u4 = sW4[f * 64 + l];
        WL.u4 = sW4[(12 + f) * 64 + l];
        f32x16& acc = (f & 1) ? accb : acca;
        acc = mfma16(WH.v, BH.v, acc);
        acc = mfma16(WL.v, BH.v, acc);
        acc = mfma16(WH.v, BL.v, acc);
    }

    // bias1 + relu  (b[row(r,g)] = quad at 8p+4g)
    float v1v[16];
    {
#pragma unroll
        for (int p = 0; p < 4; ++p) {
            f32x4 bq = *(const f32x4*)&sB[0 + 8*p + 4*g];
#pragma unroll
            for (int m = 0; m < 4; ++m)
                v1v[4*p + m] = fmaxf(acca[4*p + m] + accb[4*p + m] + bq[m], 0.f);
        }
    }
    FragU a2h[2], a2l[2];
    transition(v1v, g, a2h, a2l);

    // ---- layer 2 (W2 frags from global, L1-resident) ----
    f32x16 acc2 = zero16();
#pragma unroll
    for (int f2 = 0; f2 < 2; ++f2) {
        FragU WH, WL;
        WH.u4 = wf4[(24 + 2*f2) * 64 + l];
        WL.u4 = wf4[(25 + 2*f2) * 64 + l];
        acc2 = mfma16(WH.v, a2h[f2].v, acc2);
        acc2 = mfma16(WL.v, a2h[f2].v, acc2);
        acc2 = mfma16(WH.v, a2l[f2].v, acc2);
    }
    float v2v[16];
    {
#pragma unroll
        for (int p = 0; p < 4; ++p) {
            f32x4 bq = *(const f32x4*)&sB[32 + 8*p + 4*g];
#pragma unroll
            for (int m = 0; m < 4; ++m)
                v2v[4*p + m] = fmaxf(acc2[4*p + m] + bq[m], 0.f);
        }
    }
    FragU a3h[2], a3l[2];
    transition(v2v, g, a3h, a3l);

    // ---- layer 3 (no relu; W3 frags from global) ----
    f32x16 acc3 = zero16();
#pragma unroll
    for (int f2 = 0; f2 < 2; ++f2) {
        FragU WH, WL;
        WH.u4 = wf4[(28 + 2*f2) * 64 + l];
        WL.u4 = wf4[(29 + 2*f2) * 64 + l];
        acc3 = mfma16(WH.v, a3h[f2].v, acc3);
        acc3 = mfma16(WL.v, a3h[f2].v, acc3);
        acc3 = mfma16(WH.v, a3l[f2].v, acc3);
    }
    float v3v[16];
    {
#pragma unroll
        for (int p = 0; p < 4; ++p) {
            f32x4 bq = *(const f32x4*)&sB[64 + 8*p + 4*g];
#pragma unroll
            for (int m = 0; m < 4; ++m)
                v3v[4*p + m] = acc3[4*p + m] + bq[m];
        }
    }
    FragU a4h[2], a4l[2];
    transition(v3v, g, a4h, a4l);

    // ---- heads: 4 A-tiles (2 heads each); HW1 hi+lo from global (L1) ----
    const f32x4 hb1q0 = *(const f32x4*)&sB[96  + t_lane*16 + 4*g];
    const f32x4 hb1q1 = *(const f32x4*)&sB[96  + t_lane*16 + 8 + 4*g];
    const f32x4 hw2q0 = *(const f32x4*)&sB[224 + t_lane*16 + 4*g];
    const f32x4 hw2q1 = *(const f32x4*)&sB[224 + t_lane*16 + 8 + 4*g];

    float ys = 0.f;
#pragma unroll
    for (int n = 0; n < 4; ++n) {
        f32x16 hacc = zero16();
#pragma unroll
        for (int f2 = 0; f2 < 2; ++f2) {
            FragU WH, WL;
            WH.u4 = wf4[(32 + 4*n + 2*f2) * 64 + l];      // HW1-hi (global)
            WL.u4 = wf4[(33 + 4*n + 2*f2) * 64 + l];      // HW1-lo (global)
            hacc = mfma16(WH.v, a4h[f2].v, hacc);
            hacc = mfma16(WL.v, a4h[f2].v, hacc);
            hacc = mfma16(WH.v, a4l[f2].v, hacc);
        }
        const bool sel = ((t_lane >> 1) == n);
        const bool half = (t_lane & 1);
#pragma unroll
        for (int j = 0; j < 8; ++j) {
            const float bb = (j < 4) ? hb1q0[j] : hb1q1[j - 4];
            const float ww = (j < 4) ? hw2q0[j] : hw2q1[j - 4];
            const float c0 = fmaxf(hacc[j]     + bb, 0.f) * ww;
            const float c1 = fmaxf(hacc[8 + j] + bb, 0.f) * ww;
            const float pick = half ? c1 : c0;
            ys += sel ? pick : 0.f;
        }
    }

    const float ytot = ys + __shfl_xor(ys, 32);
    if (g == 0)
        out[arow] = ytot + sB[352 + t_lane];
}

} // namespace

extern "C" void kernel_launch(void* const* d_in, const int* in_sizes, int n_in,
                              void* d_out, int out_size, void* d_ws, size_t ws_size,
                              hipStream_t stream)
{
    const float* x_cont = (const float*)d_in[0];
    const int*   x_cate = (const int*)  d_in[1];
    const int*   t      = (const int*)  d_in[2];
    const float* emb    = (const float*)d_in[3];
    const float* W1     = (const float*)d_in[4];
    const float* b1     = (const float*)d_in[5];
    const float* W2     = (const float*)d_in[6];
    const float* b2     = (const float*)d_in[7];
    const float* W3     = (const float*)d_in[8];
    const float* b3     = (const float*)d_in[9];
    const float* HW1    = (const float*)d_in[10];
    const float* Hb1    = (const float*)d_in[11];
    const float* HW2    = (const float*)d_in[12];
    const float* Hb2    = (const float*)d_in[13];
    float* out = (float*)d_out;

    ushort* WF = (ushort*)d_ws;
    ushort* eh = (ushort*)((char*)d_ws + kOffEH);
    ushort* el = (ushort*)((char*)d_ws + kOffEL);

    hipLaunchKernelGGL(build_wfrags, dim3(12), dim3(256), 0, stream, W1, W2, W3, HW1, WF);
    hipLaunchKernelGGL(build_embsplit, dim3((kNCate*kVocab + 255)/256), dim3(256), 0, stream,
                       emb, eh, el);

    const int grid = kRows / 128;   // 4096 blocks, 128 rows each (4 waves x 32)
    hipLaunchKernelGGL(fused_main, dim3(grid), dim3(256), 0, stream,
                       x_cont, x_cate, t, WF, eh, el,
                       b1, b2, b3, Hb1, HW2, Hb2, out);
}

// Round 12
// 87.787 us; speedup vs baseline: 2.7449x; 1.1290x over previous
//
#include <hip/hip_runtime.h>

namespace {

typedef float  f32x4  __attribute__((ext_vector_type(4)));
typedef float  f32x16 __attribute__((ext_vector_type(16)));
typedef short  bf16x8 __attribute__((ext_vector_type(8)));
typedef int    i32x4  __attribute__((ext_vector_type(4)));
typedef unsigned int u32;

constexpr int kRows  = 524288;
constexpr int kCont  = 64;
constexpr int kNCate = 16;
constexpr int kVocab = 1000;
constexpr int kEm    = 8;
constexpr int kRH    = 32;
constexpr int kPH    = 16;

constexpr int    kNFrag = 48;
constexpr size_t kOffEI = (size_t)kNFrag * 1024;    // 49152; EI = 16000 x 32B

__device__ inline u32 rne_hi(float x) {
    u32 u = __float_as_uint(x);
    return ((u + 0x7fffu + ((u >> 16) & 1u)) >> 16) & 0xffffu;
}
__device__ inline float hi_f32(u32 h) { return __uint_as_float(h << 16); }
__device__ inline u32 pack2(float a, float b) {
    return rne_hi(a) | (rne_hi(b) << 16);
}

union FragU { u32 w[4]; bf16x8 v; uint4 u4; };

__device__ inline f32x16 mfma16(bf16x8 a, bf16x8 b, f32x16 c) {
    return __builtin_amdgcn_mfma_f32_32x32x16_bf16(a, b, c, 0, 0, 0);
}
__device__ inline f32x16 zero16() {
    f32x16 z;
#pragma unroll
    for (int i = 0; i < 16; ++i) z[i] = 0.f;
    return z;
}
__device__ inline void gload_lds16(const void* g, void* l) {
    __builtin_amdgcn_global_load_lds(
        (const __attribute__((address_space(1))) void*)g,
        (__attribute__((address_space(3))) void*)l, 16, 0, 0);
}

// ---------------------------------------------------------------------------
// Pre-kernel 1 (unchanged since R6 — hardware-verified frag convention).
// ---------------------------------------------------------------------------
__global__ __launch_bounds__(256) void build_wfrags(
    const float* __restrict__ W1, const float* __restrict__ W2,
    const float* __restrict__ W3, const float* __restrict__ HW1,
    ushort* __restrict__ WF)
{
    int gid = blockIdx.x * blockDim.x + threadIdx.x;
    if (gid >= kNFrag * 64) return;
    const int q = gid >> 6, l = gid & 63;
    const int lc = l & 31, g = l >> 5;

    const float* src; int k0, col, ldn, p;
    if (q < 12)      { src = W1; k0 = 16*q + 8*g;      col = lc; ldn = 32; p = 0; }
    else if (q < 24) { src = W1; k0 = 16*(q-12) + 8*g; col = lc; ldn = 32; p = 1; }
    else if (q < 28) { int u2 = q-24; src = W2; k0 = 16*(u2>>1) + 8*g; col = lc; ldn = 32; p = u2&1; }
    else if (q < 32) { int u2 = q-28; src = W3; k0 = 16*(u2>>1) + 8*g; col = lc; ldn = 32; p = u2&1; }
    else {
        int u2 = q-32; int n = u2>>2; int f = (u2>>1)&1; p = u2&1;
        int c128 = n*32 + lc; int head = c128 >> 4, ph = c128 & 15;
        src = HW1 + (size_t)head * kRH * kPH + ph;
        k0 = 16*f + 8*g; col = 0; ldn = kPH;
    }

    u32 hv[8];
#pragma unroll
    for (int j = 0; j < 8; ++j) {
        float w = src[(size_t)(k0 + j) * ldn + col];
        u32 h = rne_hi(w);
        hv[j] = (p == 0) ? h : rne_hi(w - hi_f32(h));
    }
    FragU fu;
#pragma unroll
    for (int w = 0; w < 4; ++w) fu.w[w] = hv[2*w] | (hv[2*w+1] << 16);
    ((uint4*)WF)[q * 64 + l] = fu.u4;
}

// ---------------------------------------------------------------------------
// Pre-kernel 2 (R12): emb -> INTERLEAVED 32B records {hi uint4 | lo uint4}
// so the hi and lo gathers for one (sample,cate) hit the same 64B line.
// ---------------------------------------------------------------------------
__global__ __launch_bounds__(256) void build_embint(
    const float* __restrict__ emb, ushort* __restrict__ ei)
{
    int r = blockIdx.x * blockDim.x + threadIdx.x;    // row = c*1000+v
    if (r >= kNCate * kVocab) return;
    const float* e = emb + (size_t)r * kEm;
    FragU H, L;
#pragma unroll
    for (int w = 0; w < 4; ++w) {
        float a = e[2*w], b = e[2*w+1];
        u32 ha = rne_hi(a), hb_ = rne_hi(b);
        u32 la = rne_hi(a - hi_f32(ha)), lb = rne_hi(b - hi_f32(hb_));
        H.w[w] = ha | (hb_ << 16);
        L.w[w] = la | (lb << 16);
    }
    ((uint4*)ei)[2*r]     = H.u4;
    ((uint4*)ei)[2*r + 1] = L.u4;
}

// ---------------------------------------------------------------------------
// Transition (unchanged, verified): 16 per-lane f32 -> hi/lo B-frags.
// ---------------------------------------------------------------------------
__device__ inline void transition(const float* v, int g, FragU* H, FragU* L) {
    u32 hw[8], lw[8];
#pragma unroll
    for (int p = 0; p < 8; ++p) {
        float v0 = v[2*p], v1 = v[2*p+1];
        u32 h0 = rne_hi(v0), h1 = rne_hi(v1);
        hw[p] = h0 | (h1 << 16);
        lw[p] = pack2(v0 - hi_f32(h0), v1 - hi_f32(h1));
    }
#pragma unroll
    for (int f2 = 0; f2 < 2; ++f2) {
        u32 hp[4], lp[4];
#pragma unroll
        for (int p = 0; p < 4; ++p) {
            hp[p] = (u32)__shfl_xor((int)hw[4*f2 + p], 32);
            lp[p] = (u32)__shfl_xor((int)lw[4*f2 + p], 32);
        }
        H[f2].w[0] = g ? hp[2] : hw[4*f2+0];
        H[f2].w[1] = g ? hp[3] : hw[4*f2+1];
        H[f2].w[2] = g ? hw[4*f2+2] : hp[0];
        H[f2].w[3] = g ? hw[4*f2+3] : hp[1];
        L[f2].w[0] = g ? lp[2] : lw[4*f2+0];
        L[f2].w[1] = g ? lp[3] : lw[4*f2+1];
        L[f2].w[2] = g ? lw[4*f2+2] : lp[0];
        L[f2].w[3] = g ? lw[4*f2+3] : lp[1];
    }
}

// ---------------------------------------------------------------------------
// Main kernel (R12): 256 threads = 4 waves, 1 M-tile (32 samples)/wave.
// TA-pressure cuts vs R11:
//  - x_cont: 8 coalesced global_load_lds (pre-swizzled per-lane SOURCE,
//    linear LDS dest — rule 21) into per-wave 8KB buffer; frag reads via
//    XOR-16 swizzled ds_read_b128 (4-way conflict).
//  - emb: interleaved 32B records, hi+lo share a cache line.
// LDS: W1 frags 24KB + 4x8KB xstage + tables ~1.5KB = ~58KB -> 2 blocks/CU.
// ---------------------------------------------------------------------------
__global__ __launch_bounds__(256, 2) void fused_main(
    const float* __restrict__ xc, const int* __restrict__ xcate,
    const int* __restrict__ tptr,
    const ushort* __restrict__ WF,
    const ushort* __restrict__ ei,
    const float* __restrict__ b1, const float* __restrict__ b2,
    const float* __restrict__ b3, const float* __restrict__ Hb1,
    const float* __restrict__ HW2, const float* __restrict__ Hb2,
    float* __restrict__ out)
{
    __shared__ __align__(16) uint4 sW4[24 * 64];      // 24 KB: W1 hi+lo frags
    __shared__ __align__(16) float sX[4][2048];       // 4 x 8KB x_cont stage
    __shared__ __align__(16) float sB[360];

    const int tid = threadIdx.x;
    const uint4* wf4 = (const uint4*)WF;

#pragma unroll
    for (int it = 0; it < 6; ++it) {
        const int i = tid + 256 * it;                 // q*64+l for q<24
        sW4[i] = wf4[i];
    }
    for (int i = tid; i < 360; i += 256) {
        float v;
        if      (i < 32)  v = b1[i];
        else if (i < 64)  v = b2[i - 32];
        else if (i < 96)  v = b3[i - 64];
        else if (i < 224) v = Hb1[i - 96];
        else if (i < 352) v = HW2[i - 224];
        else              v = Hb2[i - 352];
        sB[i] = v;
    }
    __syncthreads();

    const int wv = tid >> 6, l = tid & 63;
    const int lc = l & 31, g = l >> 5;
    const int tb = blockIdx.x * 128 + wv * 32;
    const int arow = tb + lc;                         // this lane's sample

    // ---- 1) stage x_cont tile (32x256B) into this wave's LDS buffer.
    // Linear LDS slot (i, lane) holds sample r = 4i + (lane>>4),
    // chunk c4' = lane&15; we pre-swizzle the SOURCE so that content is
    // chunk (lane&15) ^ (r&15)  => read addr row*256 + (c4^(r&15))*16.
    char* xb = (char*)&sX[wv][0];
    {
        const float* xbase = xc + (size_t)tb * kCont;
#pragma unroll
        for (int i = 0; i < 8; ++i) {
            const int r   = 4*i + (l >> 4);
            const int c4s = (l & 15) ^ (r & 15);
            gload_lds16(xbase + r * kCont + c4s * 4, xb + i * 1024);
        }
    }

    // ---- 2) scattered index/t loads, then emb gathers (interleaved table) --
    i32x4 cq[4];
    {
        const i32x4* cr4 = (const i32x4*)(xcate + (size_t)arow * kNCate);
#pragma unroll
        for (int q = 0; q < 4; ++q) cq[q] = cr4[q];
    }
    const int t_lane = tptr[arow];

    uint4 ehv[8], elv[8];
    {
        const uint4* ei4 = (const uint4*)ei;
#pragma unroll
        for (int i = 0; i < 8; ++i) {
            const int c   = 2*i + g;
            const int idx = cq[i >> 1][2*(i & 1) + g];
            const size_t ro = (size_t)(c * kVocab + idx) * 2;
            ehv[i] = ei4[ro];        // hi | same 64B line
            elv[i] = ei4[ro + 1];    // lo |
        }
    }

    // ---- wait for gload_lds writes before reading xb (rule 18 fence) ----
    asm volatile("s_waitcnt vmcnt(0)" ::: "memory");
    __builtin_amdgcn_sched_barrier(0);

    // ---- layer 1: acc = Wh@Xh + Wl@Xh + Wh@Xl over 12 k-frags ----
    f32x16 acca = zero16(), accb = zero16();
#pragma unroll
    for (int f = 0; f < 4; ++f) {                     // x_cont frags from LDS
        const int c0 = 4*f + 2*g;
        f32x4 va0 = *(const f32x4*)(xb + lc*256 + (((c0)     ^ (lc & 15)) * 16));
        f32x4 va1 = *(const f32x4*)(xb + lc*256 + (((c0 + 1) ^ (lc & 15)) * 16));
        FragU H, L;
#pragma unroll
        for (int w = 0; w < 4; ++w) {
            const f32x4& va = (w < 2) ? va0 : va1;
            const float v0 = va[2*(w & 1)], v1 = va[2*(w & 1) + 1];
            u32 h0 = rne_hi(v0), h1 = rne_hi(v1);
            H.w[w] = h0 | (h1 << 16);
            L.w[w] = pack2(v0 - hi_f32(h0), v1 - hi_f32(h1));
        }
        FragU WH, WL;
        WH.u4 = sW4[f * 64 + l];
        WL.u4 = sW4[(12 + f) * 64 + l];
        f32x16& acc = (f & 1) ? accb : acca;
        acc = mfma16(WH.v, H.v, acc);
        acc = mfma16(WL.v, H.v, acc);
        acc = mfma16(WH.v, L.v, acc);
    }
#pragma unroll
    for (int i = 0; i < 8; ++i) {                     // emb frags, pre-split
        const int f = 4 + i;
        FragU BH, BL, WH, WL;
        BH.u4 = ehv[i]; BL.u4 = elv[i];
        WH.u4 = sW4[f * 64 + l];
        WL.u4 = sW4[(12 + f) * 64 + l];
        f32x16& acc = (f & 1) ? accb : acca;
        acc = mfma16(WH.v, BH.v, acc);
        acc = mfma16(WL.v, BH.v, acc);
        acc = mfma16(WH.v, BL.v, acc);
    }

    // bias1 + relu
    float v1v[16];
    {
#pragma unroll
        for (int p = 0; p < 4; ++p) {
            f32x4 bq = *(const f32x4*)&sB[0 + 8*p + 4*g];
#pragma unroll
            for (int m = 0; m < 4; ++m)
                v1v[4*p + m] = fmaxf(acca[4*p + m] + accb[4*p + m] + bq[m], 0.f);
        }
    }
    FragU a2h[2], a2l[2];
    transition(v1v, g, a2h, a2l);

    // ---- layer 2 (W2 frags from global, L1-resident) ----
    f32x16 acc2 = zero16();
#pragma unroll
    for (int f2 = 0; f2 < 2; ++f2) {
        FragU WH, WL;
        WH.u4 = wf4[(24 + 2*f2) * 64 + l];
        WL.u4 = wf4[(25 + 2*f2) * 64 + l];
        acc2 = mfma16(WH.v, a2h[f2].v, acc2);
        acc2 = mfma16(WL.v, a2h[f2].v, acc2);
        acc2 = mfma16(WH.v, a2l[f2].v, acc2);
    }
    float v2v[16];
    {
#pragma unroll
        for (int p = 0; p < 4; ++p) {
            f32x4 bq = *(const f32x4*)&sB[32 + 8*p + 4*g];
#pragma unroll
            for (int m = 0; m < 4; ++m)
                v2v[4*p + m] = fmaxf(acc2[4*p + m] + bq[m], 0.f);
        }
    }
    FragU a3h[2], a3l[2];
    transition(v2v, g, a3h, a3l);

    // ---- layer 3 (no relu; W3 frags from global) ----
    f32x16 acc3 = zero16();
#pragma unroll
    for (int f2 = 0; f2 < 2; ++f2) {
        FragU WH, WL;
        WH.u4 = wf4[(28 + 2*f2) * 64 + l];
        WL.u4 = wf4[(29 + 2*f2) * 64 + l];
        acc3 = mfma16(WH.v, a3h[f2].v, acc3);
        acc3 = mfma16(WL.v, a3h[f2].v, acc3);
        acc3 = mfma16(WH.v, a3l[f2].v, acc3);
    }
    float v3v[16];
    {
#pragma unroll
        for (int p = 0; p < 4; ++p) {
            f32x4 bq = *(const f32x4*)&sB[64 + 8*p + 4*g];
#pragma unroll
            for (int m = 0; m < 4; ++m)
                v3v[4*p + m] = acc3[4*p + m] + bq[m];
        }
    }
    FragU a4h[2], a4l[2];
    transition(v3v, g, a4h, a4l);

    // ---- heads: 4 A-tiles (2 heads each); HW1 hi+lo from global (L1) ----
    const f32x4 hb1q0 = *(const f32x4*)&sB[96  + t_lane*16 + 4*g];
    const f32x4 hb1q1 = *(const f32x4*)&sB[96  + t_lane*16 + 8 + 4*g];
    const f32x4 hw2q0 = *(const f32x4*)&sB[224 + t_lane*16 + 4*g];
    const f32x4 hw2q1 = *(const f32x4*)&sB[224 + t_lane*16 + 8 + 4*g];

    float ys = 0.f;
#pragma unroll
    for (int n = 0; n < 4; ++n) {
        f32x16 hacc = zero16();
#pragma unroll
        for (int f2 = 0; f2 < 2; ++f2) {
            FragU WH, WL;
            WH.u4 = wf4[(32 + 4*n + 2*f2) * 64 + l];
            WL.u4 = wf4[(33 + 4*n + 2*f2) * 64 + l];
            hacc = mfma16(WH.v, a4h[f2].v, hacc);
            hacc = mfma16(WL.v, a4h[f2].v, hacc);
            hacc = mfma16(WH.v, a4l[f2].v, hacc);
        }
        const bool sel = ((t_lane >> 1) == n);
        const bool half = (t_lane & 1);
#pragma unroll
        for (int j = 0; j < 8; ++j) {
            const float bb = (j < 4) ? hb1q0[j] : hb1q1[j - 4];
            const float ww = (j < 4) ? hw2q0[j] : hw2q1[j - 4];
            const float c0 = fmaxf(hacc[j]     + bb, 0.f) * ww;
            const float c1 = fmaxf(hacc[8 + j] + bb, 0.f) * ww;
            const float pick = half ? c1 : c0;
            ys += sel ? pick : 0.f;
        }
    }

    const float ytot = ys + __shfl_xor(ys, 32);
    if (g == 0)
        out[arow] = ytot + sB[352 + t_lane];
}

} // namespace

extern "C" void kernel_launch(void* const* d_in, const int* in_sizes, int n_in,
                              void* d_out, int out_size, void* d_ws, size_t ws_size,
                              hipStream_t stream)
{
    const float* x_cont = (const float*)d_in[0];
    const int*   x_cate = (const int*)  d_in[1];
    const int*   t      = (const int*)  d_in[2];
    const float* emb    = (const float*)d_in[3];
    const float* W1     = (const float*)d_in[4];
    const float* b1     = (const float*)d_in[5];
    const float* W2     = (const float*)d_in[6];
    const float* b2     = (const float*)d_in[7];
    const float* W3     = (const float*)d_in[8];
    const float* b3     = (const float*)d_in[9];
    const float* HW1    = (const float*)d_in[10];
    const float* Hb1    = (const float*)d_in[11];
    const float* HW2    = (const float*)d_in[12];
    const float* Hb2    = (const float*)d_in[13];
    float* out = (float*)d_out;

    ushort* WF = (ushort*)d_ws;
    ushort* ei = (ushort*)((char*)d_ws + kOffEI);

    hipLaunchKernelGGL(build_wfrags, dim3(12), dim3(256), 0, stream, W1, W2, W3, HW1, WF);
    hipLaunchKernelGGL(build_embint, dim3((kNCate*kVocab + 255)/256), dim3(256), 0, stream,
                       emb, ei);

    const int grid = kRows / 128;   // 4096 blocks, 128 rows each (4 waves x 32)
    hipLaunchKernelGGL(fused_main, dim3(grid), dim3(256), 0, stream,
                       x_cont, x_cate, t, WF, ei,
                       b1, b2, b3, Hb1, HW2, Hb2, out);
}

// Round 13
// 77.378 us; speedup vs baseline: 3.1142x; 1.1345x over previous
//
#include <hip/hip_runtime.h>

namespace {

typedef float  f32x4  __attribute__((ext_vector_type(4)));
typedef float  f32x16 __attribute__((ext_vector_type(16)));
typedef short  bf16x8 __attribute__((ext_vector_type(8)));
typedef int    i32x4  __attribute__((ext_vector_type(4)));
typedef unsigned int u32;

constexpr int kRows  = 524288;
constexpr int kCont  = 64;
constexpr int kNCate = 16;
constexpr int kVocab = 1000;
constexpr int kEm    = 8;
constexpr int kRH    = 32;
constexpr int kPH    = 16;

constexpr int    kNFrag = 48;
constexpr size_t kOffEH = (size_t)kNFrag * 1024;    // 49152; EH = 16000 x 16B

__device__ inline u32 rne_hi(float x) {
    u32 u = __float_as_uint(x);
    return ((u + 0x7fffu + ((u >> 16) & 1u)) >> 16) & 0xffffu;
}
__device__ inline float hi_f32(u32 h) { return __uint_as_float(h << 16); }
__device__ inline u32 pack2(float a, float b) {
    return rne_hi(a) | (rne_hi(b) << 16);
}

union FragU { u32 w[4]; bf16x8 v; uint4 u4; };

__device__ inline f32x16 mfma16(bf16x8 a, bf16x8 b, f32x16 c) {
    return __builtin_amdgcn_mfma_f32_32x32x16_bf16(a, b, c, 0, 0, 0);
}
__device__ inline f32x16 zero16() {
    f32x16 z;
#pragma unroll
    for (int i = 0; i < 16; ++i) z[i] = 0.f;
    return z;
}
__device__ inline void gload_lds16(const void* g, void* l) {
    __builtin_amdgcn_global_load_lds(
        (const __attribute__((address_space(1))) void*)g,
        (__attribute__((address_space(3))) void*)l, 16, 0, 0);
}

// ---------------------------------------------------------------------------
// Pre-kernel 1 (R13): same frag table as R6 EXCEPT the emb range of W1
// (k rows 64..191) uses the permuted mapping k0 = 64 + 8*(f-4) + 64*g so
// that lane-group g owns cates i+8g (contiguous per lane on the B side).
// Cont range (f<4) unchanged; W2/W3/HW1 unchanged.
// ---------------------------------------------------------------------------
__global__ __launch_bounds__(256) void build_wfrags(
    const float* __restrict__ W1, const float* __restrict__ W2,
    const float* __restrict__ W3, const float* __restrict__ HW1,
    ushort* __restrict__ WF)
{
    int gid = blockIdx.x * blockDim.x + threadIdx.x;
    if (gid >= kNFrag * 64) return;
    const int q = gid >> 6, l = gid & 63;
    const int lc = l & 31, g = l >> 5;

    const float* src; int k0, col, ldn, p;
    if (q < 12) {
        src = W1; col = lc; ldn = 32; p = 0;
        k0 = (q < 4) ? (16*q + 8*g) : (64 + 8*(q - 4) + 64*g);
    } else if (q < 24) {
        int f = q - 12;
        src = W1; col = lc; ldn = 32; p = 1;
        k0 = (f < 4) ? (16*f + 8*g) : (64 + 8*(f - 4) + 64*g);
    }
    else if (q < 28) { int u2 = q-24; src = W2; k0 = 16*(u2>>1) + 8*g; col = lc; ldn = 32; p = u2&1; }
    else if (q < 32) { int u2 = q-28; src = W3; k0 = 16*(u2>>1) + 8*g; col = lc; ldn = 32; p = u2&1; }
    else {
        int u2 = q-32; int n = u2>>2; int f = (u2>>1)&1; p = u2&1;
        int c128 = n*32 + lc; int head = c128 >> 4, ph = c128 & 15;
        src = HW1 + (size_t)head * kRH * kPH + ph;
        k0 = 16*f + 8*g; col = 0; ldn = kPH;
    }

    u32 hv[8];
#pragma unroll
    for (int j = 0; j < 8; ++j) {
        float w = src[(size_t)(k0 + j) * ldn + col];
        u32 h = rne_hi(w);
        hv[j] = (p == 0) ? h : rne_hi(w - hi_f32(h));
    }
    FragU fu;
#pragma unroll
    for (int w = 0; w < 4; ++w) fu.w[w] = hv[2*w] | (hv[2*w+1] << 16);
    ((uint4*)WF)[q * 64 + l] = fu.u4;
}

// ---------------------------------------------------------------------------
// Pre-kernel 2 (R13): emb -> bf16 HI-ONLY table, 16B records.
// (emb cross terms dropped: error ~5e-7 at y, threshold 8.4e-5.)
// ---------------------------------------------------------------------------
__global__ __launch_bounds__(256) void build_embhi(
    const float* __restrict__ emb, ushort* __restrict__ eh)
{
    int r = blockIdx.x * blockDim.x + threadIdx.x;    // row = c*1000+v
    if (r >= kNCate * kVocab) return;
    const float* e = emb + (size_t)r * kEm;
    FragU H;
#pragma unroll
    for (int w = 0; w < 4; ++w)
        H.w[w] = pack2(e[2*w], e[2*w+1]);
    ((uint4*)eh)[r] = H.u4;
}

// ---------------------------------------------------------------------------
// Transition (unchanged, verified): 16 per-lane f32 -> hi/lo B-frags.
// ---------------------------------------------------------------------------
__device__ inline void transition(const float* v, int g, FragU* H, FragU* L) {
    u32 hw[8], lw[8];
#pragma unroll
    for (int p = 0; p < 8; ++p) {
        float v0 = v[2*p], v1 = v[2*p+1];
        u32 h0 = rne_hi(v0), h1 = rne_hi(v1);
        hw[p] = h0 | (h1 << 16);
        lw[p] = pack2(v0 - hi_f32(h0), v1 - hi_f32(h1));
    }
#pragma unroll
    for (int f2 = 0; f2 < 2; ++f2) {
        u32 hp[4], lp[4];
#pragma unroll
        for (int p = 0; p < 4; ++p) {
            hp[p] = (u32)__shfl_xor((int)hw[4*f2 + p], 32);
            lp[p] = (u32)__shfl_xor((int)lw[4*f2 + p], 32);
        }
        H[f2].w[0] = g ? hp[2] : hw[4*f2+0];
        H[f2].w[1] = g ? hp[3] : hw[4*f2+1];
        H[f2].w[2] = g ? hw[4*f2+2] : hp[0];
        H[f2].w[3] = g ? hw[4*f2+3] : hp[1];
        L[f2].w[0] = g ? lp[2] : lw[4*f2+0];
        L[f2].w[1] = g ? lp[3] : lw[4*f2+1];
        L[f2].w[2] = g ? lw[4*f2+2] : lp[0];
        L[f2].w[3] = g ? lw[4*f2+3] : lp[1];
    }
}

// ---------------------------------------------------------------------------
// Main kernel (R13). TA cuts vs R12:
//  - emb: hi-only -> 8 scattered gathers/tile (was 16); 1 MFMA per emb frag.
//  - x_cate: permuted cate->lane map -> 2 loads/lane (was 4).
//  - x_cont: staged via coalesced global_load_lds (as R12).
// LDS: W1hi(12)+W1lo-cont(4) frags 16KB + 32KB xstage + 1.5KB = ~50KB
//  -> 3 blocks/CU = 12 waves.
// ---------------------------------------------------------------------------
__global__ __launch_bounds__(256, 2) void fused_main(
    const float* __restrict__ xc, const int* __restrict__ xcate,
    const int* __restrict__ tptr,
    const ushort* __restrict__ WF,
    const ushort* __restrict__ eh,
    const float* __restrict__ b1, const float* __restrict__ b2,
    const float* __restrict__ b3, const float* __restrict__ Hb1,
    const float* __restrict__ HW2, const float* __restrict__ Hb2,
    float* __restrict__ out)
{
    __shared__ __align__(16) uint4 sW4[16 * 64];      // 16 KB: W1hi q0..11, W1lo q12..15
    __shared__ __align__(16) float sX[4][2048];       // 4 x 8KB x_cont stage
    __shared__ __align__(16) float sB[360];

    const int tid = threadIdx.x;
    const uint4* wf4 = (const uint4*)WF;

#pragma unroll
    for (int it = 0; it < 4; ++it) {
        const int i = tid + 256 * it;                 // q*64+l for q<16
        sW4[i] = wf4[i];
    }
    for (int i = tid; i < 360; i += 256) {
        float v;
        if      (i < 32)  v = b1[i];
        else if (i < 64)  v = b2[i - 32];
        else if (i < 96)  v = b3[i - 64];
        else if (i < 224) v = Hb1[i - 96];
        else if (i < 352) v = HW2[i - 224];
        else              v = Hb2[i - 352];
        sB[i] = v;
    }
    __syncthreads();

    const int wv = tid >> 6, l = tid & 63;
    const int lc = l & 31, g = l >> 5;
    const int tb = blockIdx.x * 128 + wv * 32;
    const int arow = tb + lc;                         // this lane's sample

    // ---- 1) stage x_cont tile (32x256B) into this wave's LDS buffer
    // (pre-swizzled SOURCE, linear dest; read back with matching XOR).
    char* xb = (char*)&sX[wv][0];
    {
        const float* xbase = xc + (size_t)tb * kCont;
#pragma unroll
        for (int i = 0; i < 8; ++i) {
            const int r   = 4*i + (l >> 4);
            const int c4s = (l & 15) ^ (r & 15);
            gload_lds16(xbase + r * kCont + c4s * 4, xb + i * 1024);
        }
    }

    // ---- 2) per-lane indices: 8 contiguous cates starting at 8g ----
    i32x4 iq[2];
    {
        const i32x4* cr4 = (const i32x4*)(xcate + (size_t)arow * kNCate + 8*g);
        iq[0] = cr4[0];
        iq[1] = cr4[1];
    }
    const int t_lane = tptr[arow];

    uint4 ehv[8];
    {
        const uint4* eh4 = (const uint4*)eh;
#pragma unroll
        for (int i = 0; i < 8; ++i) {
            const int c   = i + 8*g;                  // permuted mapping
            const int idx = (i < 4) ? iq[0][i] : iq[1][i - 4];
            ehv[i] = eh4[(size_t)(c * kVocab + idx)];
        }
    }

    // ---- wait for gload_lds writes before reading xb ----
    asm volatile("s_waitcnt vmcnt(0)" ::: "memory");
    __builtin_amdgcn_sched_barrier(0);

    // ---- layer 1 ----
    f32x16 acca = zero16(), accb = zero16();
#pragma unroll
    for (int f = 0; f < 4; ++f) {                     // x_cont frags: 3 terms
        const int c0 = 4*f + 2*g;
        f32x4 va0 = *(const f32x4*)(xb + lc*256 + (((c0)     ^ (lc & 15)) * 16));
        f32x4 va1 = *(const f32x4*)(xb + lc*256 + (((c0 + 1) ^ (lc & 15)) * 16));
        FragU H, L;
#pragma unroll
        for (int w = 0; w < 4; ++w) {
            const f32x4& va = (w < 2) ? va0 : va1;
            const float v0 = va[2*(w & 1)], v1 = va[2*(w & 1) + 1];
            u32 h0 = rne_hi(v0), h1 = rne_hi(v1);
            H.w[w] = h0 | (h1 << 16);
            L.w[w] = pack2(v0 - hi_f32(h0), v1 - hi_f32(h1));
        }
        FragU WH, WL;
        WH.u4 = sW4[f * 64 + l];
        WL.u4 = sW4[(12 + f) * 64 + l];
        f32x16& acc = (f & 1) ? accb : acca;
        acc = mfma16(WH.v, H.v, acc);
        acc = mfma16(WL.v, H.v, acc);
        acc = mfma16(WH.v, L.v, acc);
    }
#pragma unroll
    for (int i = 0; i < 8; ++i) {                     // emb frags: hi*hi only
        const int f = 4 + i;
        FragU BH, WH;
        BH.u4 = ehv[i];
        WH.u4 = sW4[f * 64 + l];
        f32x16& acc = (f & 1) ? accb : acca;
        acc = mfma16(WH.v, BH.v, acc);
    }

    // bias1 + relu
    float v1v[16];
    {
#pragma unroll
        for (int p = 0; p < 4; ++p) {
            f32x4 bq = *(const f32x4*)&sB[0 + 8*p + 4*g];
#pragma unroll
            for (int m = 0; m < 4; ++m)
                v1v[4*p + m] = fmaxf(acca[4*p + m] + accb[4*p + m] + bq[m], 0.f);
        }
    }
    FragU a2h[2], a2l[2];
    transition(v1v, g, a2h, a2l);

    // ---- layer 2 (W2 frags from global, L1-resident) ----
    f32x16 acc2 = zero16();
#pragma unroll
    for (int f2 = 0; f2 < 2; ++f2) {
        FragU WH, WL;
        WH.u4 = wf4[(24 + 2*f2) * 64 + l];
        WL.u4 = wf4[(25 + 2*f2) * 64 + l];
        acc2 = mfma16(WH.v, a2h[f2].v, acc2);
        acc2 = mfma16(WL.v, a2h[f2].v, acc2);
        acc2 = mfma16(WH.v, a2l[f2].v, acc2);
    }
    float v2v[16];
    {
#pragma unroll
        for (int p = 0; p < 4; ++p) {
            f32x4 bq = *(const f32x4*)&sB[32 + 8*p + 4*g];
#pragma unroll
            for (int m = 0; m < 4; ++m)
                v2v[4*p + m] = fmaxf(acc2[4*p + m] + bq[m], 0.f);
        }
    }
    FragU a3h[2], a3l[2];
    transition(v2v, g, a3h, a3l);

    // ---- layer 3 (no relu; W3 frags from global) ----
    f32x16 acc3 = zero16();
#pragma unroll
    for (int f2 = 0; f2 < 2; ++f2) {
        FragU WH, WL;
        WH.u4 = wf4[(28 + 2*f2) * 64 + l];
        WL.u4 = wf4[(29 + 2*f2) * 64 + l];
        acc3 = mfma16(WH.v, a3h[f2].v, acc3);
        acc3 = mfma16(WL.v, a3h[f2].v, acc3);
        acc3 = mfma16(WH.v, a3l[f2].v, acc3);
    }
    float v3v[16];
    {
#pragma unroll
        for (int p = 0; p < 4; ++p) {
            f32x4 bq = *(const f32x4*)&sB[64 + 8*p + 4*g];
#pragma unroll
            for (int m = 0; m < 4; ++m)
                v3v[4*p + m] = acc3[4*p + m] + bq[m];
        }
    }
    FragU a4h[2], a4l[2];
    transition(v3v, g, a4h, a4l);

    // ---- heads: 4 A-tiles (2 heads each); HW1 hi+lo from global (L1) ----
    const f32x4 hb1q0 = *(const f32x4*)&sB[96  + t_lane*16 + 4*g];
    const f32x4 hb1q1 = *(const f32x4*)&sB[96  + t_lane*16 + 8 + 4*g];
    const f32x4 hw2q0 = *(const f32x4*)&sB[224 + t_lane*16 + 4*g];
    const f32x4 hw2q1 = *(const f32x4*)&sB[224 + t_lane*16 + 8 + 4*g];

    float ys = 0.f;
#pragma unroll
    for (int n = 0; n < 4; ++n) {
        f32x16 hacc = zero16();
#pragma unroll
        for (int f2 = 0; f2 < 2; ++f2) {
            FragU WH, WL;
            WH.u4 = wf4[(32 + 4*n + 2*f2) * 64 + l];
            WL.u4 = wf4[(33 + 4*n + 2*f2) * 64 + l];
            hacc = mfma16(WH.v, a4h[f2].v, hacc);
            hacc = mfma16(WL.v, a4h[f2].v, hacc);
            hacc = mfma16(WH.v, a4l[f2].v, hacc);
        }
        const bool sel = ((t_lane >> 1) == n);
        const bool half = (t_lane & 1);
#pragma unroll
        for (int j = 0; j < 8; ++j) {
            const float bb = (j < 4) ? hb1q0[j] : hb1q1[j - 4];
            const float ww = (j < 4) ? hw2q0[j] : hw2q1[j - 4];
            const float c0 = fmaxf(hacc[j]     + bb, 0.f) * ww;
            const float c1 = fmaxf(hacc[8 + j] + bb, 0.f) * ww;
            const float pick = half ? c1 : c0;
            ys += sel ? pick : 0.f;
        }
    }

    const float ytot = ys + __shfl_xor(ys, 32);
    if (g == 0)
        out[arow] = ytot + sB[352 + t_lane];
}

} // namespace

extern "C" void kernel_launch(void* const* d_in, const int* in_sizes, int n_in,
                              void* d_out, int out_size, void* d_ws, size_t ws_size,
                              hipStream_t stream)
{
    const float* x_cont = (const float*)d_in[0];
    const int*   x_cate = (const int*)  d_in[1];
    const int*   t      = (const int*)  d_in[2];
    const float* emb    = (const float*)d_in[3];
    const float* W1     = (const float*)d_in[4];
    const float* b1     = (const float*)d_in[5];
    const float* W2     = (const float*)d_in[6];
    const float* b2     = (const float*)d_in[7];
    const float* W3     = (const float*)d_in[8];
    const float* b3     = (const float*)d_in[9];
    const float* HW1    = (const float*)d_in[10];
    const float* Hb1    = (const float*)d_in[11];
    const float* HW2    = (const float*)d_in[12];
    const float* Hb2    = (const float*)d_in[13];
    float* out = (float*)d_out;

    ushort* WF = (ushort*)d_ws;
    ushort* eh = (ushort*)((char*)d_ws + kOffEH);

    hipLaunchKernelGGL(build_wfrags, dim3(12), dim3(256), 0, stream, W1, W2, W3, HW1, WF);
    hipLaunchKernelGGL(build_embhi, dim3((kNCate*kVocab + 255)/256), dim3(256), 0, stream,
                       emb, eh);

    const int grid = kRows / 128;   // 4096 blocks, 128 rows each (4 waves x 32)
    hipLaunchKernelGGL(fused_main, dim3(grid), dim3(256), 0, stream,
                       x_cont, x_cate, t, WF, eh,
                       b1, b2, b3, Hb1, HW2, Hb2, out);
}

// Round 16
// 74.884 us; speedup vs baseline: 3.2179x; 1.0333x over previous
//
#include <hip/hip_runtime.h>

namespace {

typedef float  f32x4  __attribute__((ext_vector_type(4)));
typedef float  f32x16 __attribute__((ext_vector_type(16)));
typedef short  bf16x8 __attribute__((ext_vector_type(8)));
typedef int    i32x4  __attribute__((ext_vector_type(4)));
typedef unsigned int u32;

constexpr int kRows  = 524288;
constexpr int kCont  = 64;
constexpr int kNCate = 16;
constexpr int kVocab = 1000;
constexpr int kEm    = 8;
constexpr int kRH    = 32;
constexpr int kPH    = 16;

constexpr int    kNFrag = 48;
constexpr size_t kOffEH = (size_t)kNFrag * 1024;    // 49152; EH = 16000 x 16B

__device__ inline u32 rne_hi(float x) {
    u32 u = __float_as_uint(x);
    return ((u + 0x7fffu + ((u >> 16) & 1u)) >> 16) & 0xffffu;
}
__device__ inline float hi_f32(u32 h) { return __uint_as_float(h << 16); }
__device__ inline u32 pack2(float a, float b) {
    return rne_hi(a) | (rne_hi(b) << 16);
}

union FragU { u32 w[4]; bf16x8 v; uint4 u4; };

__device__ inline f32x16 mfma16(bf16x8 a, bf16x8 b, f32x16 c) {
    return __builtin_amdgcn_mfma_f32_32x32x16_bf16(a, b, c, 0, 0, 0);
}
__device__ inline f32x16 zero16() {
    f32x16 z;
#pragma unroll
    for (int i = 0; i < 16; ++i) z[i] = 0.f;
    return z;
}
__device__ inline void gload_lds16(const void* g, void* l) {
    __builtin_amdgcn_global_load_lds(
        (const __attribute__((address_space(1))) void*)g,
        (__attribute__((address_space(3))) void*)l, 16, 0, 0);
}
__device__ inline void fence_vm0() {
    asm volatile("s_waitcnt vmcnt(0)" ::: "memory");
    __builtin_amdgcn_sched_barrier(0);
}
__device__ inline void fence_lgkm0() {
    asm volatile("s_waitcnt lgkmcnt(0)" ::: "memory");
    __builtin_amdgcn_sched_barrier(0);
}

// ---------------------------------------------------------------------------
// Pre-kernel 1 (R13 mapping, unchanged): W1 emb range permuted
// (k0 = 64 + 8*(f-4) + 64*g); cont range and W2/W3/HW1 as R6.
// ---------------------------------------------------------------------------
__global__ __launch_bounds__(256) void build_wfrags(
    const float* __restrict__ W1, const float* __restrict__ W2,
    const float* __restrict__ W3, const float* __restrict__ HW1,
    ushort* __restrict__ WF)
{
    int gid = blockIdx.x * blockDim.x + threadIdx.x;
    if (gid >= kNFrag * 64) return;
    const int q = gid >> 6, l = gid & 63;
    const int lc = l & 31, g = l >> 5;

    const float* src; int k0, col, ldn, p;
    if (q < 12) {
        src = W1; col = lc; ldn = 32; p = 0;
        k0 = (q < 4) ? (16*q + 8*g) : (64 + 8*(q - 4) + 64*g);
    } else if (q < 24) {
        int f = q - 12;
        src = W1; col = lc; ldn = 32; p = 1;
        k0 = (f < 4) ? (16*f + 8*g) : (64 + 8*(f - 4) + 64*g);
    }
    else if (q < 28) { int u2 = q-24; src = W2; k0 = 16*(u2>>1) + 8*g; col = lc; ldn = 32; p = u2&1; }
    else if (q < 32) { int u2 = q-28; src = W3; k0 = 16*(u2>>1) + 8*g; col = lc; ldn = 32; p = u2&1; }
    else {
        int u2 = q-32; int n = u2>>2; int f = (u2>>1)&1; p = u2&1;
        int c128 = n*32 + lc; int head = c128 >> 4, ph = c128 & 15;
        src = HW1 + (size_t)head * kRH * kPH + ph;
        k0 = 16*f + 8*g; col = 0; ldn = kPH;
    }

    u32 hv[8];
#pragma unroll
    for (int j = 0; j < 8; ++j) {
        float w = src[(size_t)(k0 + j) * ldn + col];
        u32 h = rne_hi(w);
        hv[j] = (p == 0) ? h : rne_hi(w - hi_f32(h));
    }
    FragU fu;
#pragma unroll
    for (int w = 0; w < 4; ++w) fu.w[w] = hv[2*w] | (hv[2*w+1] << 16);
    ((uint4*)WF)[q * 64 + l] = fu.u4;
}

// ---------------------------------------------------------------------------
// Pre-kernel 2 (unchanged R13): emb -> bf16 HI-ONLY table, 16B records.
// ---------------------------------------------------------------------------
__global__ __launch_bounds__(256) void build_embhi(
    const float* __restrict__ emb, ushort* __restrict__ eh)
{
    int r = blockIdx.x * blockDim.x + threadIdx.x;
    if (r >= kNCate * kVocab) return;
    const float* e = emb + (size_t)r * kEm;
    FragU H;
#pragma unroll
    for (int w = 0; w < 4; ++w)
        H.w[w] = pack2(e[2*w], e[2*w+1]);
    ((uint4*)eh)[r] = H.u4;
}

// ---------------------------------------------------------------------------
// Transition (unchanged, verified).
// ---------------------------------------------------------------------------
__device__ inline void transition(const float* v, int g, FragU* H, FragU* L) {
    u32 hw[8], lw[8];
#pragma unroll
    for (int p = 0; p < 8; ++p) {
        float v0 = v[2*p], v1 = v[2*p+1];
        u32 h0 = rne_hi(v0), h1 = rne_hi(v1);
        hw[p] = h0 | (h1 << 16);
        lw[p] = pack2(v0 - hi_f32(h0), v1 - hi_f32(h1));
    }
#pragma unroll
    for (int f2 = 0; f2 < 2; ++f2) {
        u32 hp[4], lp[4];
#pragma unroll
        for (int p = 0; p < 4; ++p) {
            hp[p] = (u32)__shfl_xor((int)hw[4*f2 + p], 32);
            lp[p] = (u32)__shfl_xor((int)lw[4*f2 + p], 32);
        }
        H[f2].w[0] = g ? hp[2] : hw[4*f2+0];
        H[f2].w[1] = g ? hp[3] : hw[4*f2+1];
        H[f2].w[2] = g ? hw[4*f2+2] : hp[0];
        H[f2].w[3] = g ? hw[4*f2+3] : hp[1];
        L[f2].w[0] = g ? lp[2] : lw[4*f2+0];
        L[f2].w[1] = g ? lp[3] : lw[4*f2+1];
        L[f2].w[2] = g ? lw[4*f2+2] : lp[0];
        L[f2].w[3] = g ? lw[4*f2+3] : lp[1];
    }
}

// ---------------------------------------------------------------------------
// Main kernel (R14 resubmit x2): 2 tiles per wave, software-pipelined.
//   t1: stage+idx -> fence -> [issue emb1] cont1 -> [lgkm0, stage2+idx2]
//       emb1-MFMA, mid1 -> [issue emb2] heads1+store1 -> fence ->
//   t2: cont2, emb2-MFMA, mid2, heads2+store2.
// Gather/staging latency hides under compute of the other phase.
// ---------------------------------------------------------------------------
__global__ __launch_bounds__(256, 3) void fused_main(
    const float* __restrict__ xc, const int* __restrict__ xcate,
    const int* __restrict__ tptr,
    const ushort* __restrict__ WF,
    const ushort* __restrict__ eh,
    const float* __restrict__ b1, const float* __restrict__ b2,
    const float* __restrict__ b3, const float* __restrict__ Hb1,
    const float* __restrict__ HW2, const float* __restrict__ Hb2,
    float* __restrict__ out)
{
    __shared__ __align__(16) uint4 sW4[16 * 64];      // 16 KB: W1hi 0..11, W1lo-cont 12..15
    __shared__ __align__(16) float sX[4][2048];       // 4 x 8KB x_cont stage
    __shared__ __align__(16) float sB[360];

    const int tid = threadIdx.x;
    const uint4* wf4 = (const uint4*)WF;

#pragma unroll
    for (int it = 0; it < 4; ++it) {
        const int i = tid + 256 * it;
        sW4[i] = wf4[i];
    }
    for (int i = tid; i < 360; i += 256) {
        float v;
        if      (i < 32)  v = b1[i];
        else if (i < 64)  v = b2[i - 32];
        else if (i < 96)  v = b3[i - 64];
        else if (i < 224) v = Hb1[i - 96];
        else if (i < 352) v = HW2[i - 224];
        else              v = Hb2[i - 352];
        sB[i] = v;
    }
    __syncthreads();

    const int wv = tid >> 6, l = tid & 63;
    const int lc = l & 31, g = l >> 5;
    const int rowbase = blockIdx.x * 256 + wv * 64;   // 2 tiles of 32
    char* xb = (char*)&sX[wv][0];
    const uint4* eh4 = (const uint4*)eh;

    // ---------------- helpers (lambdas, statically unrolled) ----------------
    auto stage_x = [&](int tbase) {
        const float* xbase = xc + (size_t)tbase * kCont;
#pragma unroll
        for (int i = 0; i < 8; ++i) {
            const int r   = 4*i + (l >> 4);
            const int c4s = (l & 15) ^ (r & 15);
            gload_lds16(xbase + r * kCont + c4s * 4, xb + i * 1024);
        }
    };
    auto load_idx = [&](int tbase, i32x4* iq, int& t_lane) {
        const i32x4* cr4 = (const i32x4*)(xcate + (size_t)(tbase + lc) * kNCate + 8*g);
        iq[0] = cr4[0];
        iq[1] = cr4[1];
        t_lane = tptr[tbase + lc];
    };
    auto gather_emb = [&](const i32x4* iq, uint4* ehv) {
#pragma unroll
        for (int i = 0; i < 8; ++i) {
            const int c   = i + 8*g;
            const int idx = (i < 4) ? iq[0][i] : iq[1][i - 4];
            ehv[i] = eh4[(size_t)(c * kVocab + idx)];
        }
    };
    auto layer1_cont = [&](f32x16& acca, f32x16& accb) {
#pragma unroll
        for (int f = 0; f < 4; ++f) {
            const int c0 = 4*f + 2*g;
            f32x4 va0 = *(const f32x4*)(xb + lc*256 + (((c0)     ^ (lc & 15)) * 16));
            f32x4 va1 = *(const f32x4*)(xb + lc*256 + (((c0 + 1) ^ (lc & 15)) * 16));
            FragU H, L;
#pragma unroll
            for (int w = 0; w < 4; ++w) {
                const f32x4& va = (w < 2) ? va0 : va1;
                const float v0 = va[2*(w & 1)], v1 = va[2*(w & 1) + 1];
                u32 h0 = rne_hi(v0), h1 = rne_hi(v1);
                H.w[w] = h0 | (h1 << 16);
                L.w[w] = pack2(v0 - hi_f32(h0), v1 - hi_f32(h1));
            }
            FragU WH, WL;
            WH.u4 = sW4[f * 64 + l];
            WL.u4 = sW4[(12 + f) * 64 + l];
            f32x16& acc = (f & 1) ? accb : acca;
            acc = mfma16(WH.v, H.v, acc);
            acc = mfma16(WL.v, H.v, acc);
            acc = mfma16(WH.v, L.v, acc);
        }
    };
    auto layer1_emb = [&](const uint4* ehv, f32x16& acca, f32x16& accb) {
#pragma unroll
        for (int i = 0; i < 8; ++i) {
            const int f = 4 + i;
            FragU BH, WH;
            BH.u4 = ehv[i];
            WH.u4 = sW4[f * 64 + l];
            f32x16& acc = (f & 1) ? accb : acca;
            acc = mfma16(WH.v, BH.v, acc);
        }
    };
    auto mid = [&](const f32x16& acca, const f32x16& accb, FragU* a4h, FragU* a4l) {
        float v1v[16];
#pragma unroll
        for (int p = 0; p < 4; ++p) {
            f32x4 bq = *(const f32x4*)&sB[0 + 8*p + 4*g];
#pragma unroll
            for (int m = 0; m < 4; ++m)
                v1v[4*p + m] = fmaxf(acca[4*p + m] + accb[4*p + m] + bq[m], 0.f);
        }
        FragU a2h[2], a2l[2];
        transition(v1v, g, a2h, a2l);

        f32x16 acc2 = zero16();
#pragma unroll
        for (int f2 = 0; f2 < 2; ++f2) {
            FragU WH, WL;
            WH.u4 = wf4[(24 + 2*f2) * 64 + l];
            WL.u4 = wf4[(25 + 2*f2) * 64 + l];
            acc2 = mfma16(WH.v, a2h[f2].v, acc2);
            acc2 = mfma16(WL.v, a2h[f2].v, acc2);
            acc2 = mfma16(WH.v, a2l[f2].v, acc2);
        }
        float v2v[16];
#pragma unroll
        for (int p = 0; p < 4; ++p) {
            f32x4 bq = *(const f32x4*)&sB[32 + 8*p + 4*g];
#pragma unroll
            for (int m = 0; m < 4; ++m)
                v2v[4*p + m] = fmaxf(acc2[4*p + m] + bq[m], 0.f);
        }
        FragU a3h[2], a3l[2];
        transition(v2v, g, a3h, a3l);

        f32x16 acc3 = zero16();
#pragma unroll
        for (int f2 = 0; f2 < 2; ++f2) {
            FragU WH, WL;
            WH.u4 = wf4[(28 + 2*f2) * 64 + l];
            WL.u4 = wf4[(29 + 2*f2) * 64 + l];
            acc3 = mfma16(WH.v, a3h[f2].v, acc3);
            acc3 = mfma16(WL.v, a3h[f2].v, acc3);
            acc3 = mfma16(WH.v, a3l[f2].v, acc3);
        }
        float v3v[16];
#pragma unroll
        for (int p = 0; p < 4; ++p) {
            f32x4 bq = *(const f32x4*)&sB[64 + 8*p + 4*g];
#pragma unroll
            for (int m = 0; m < 4; ++m)
                v3v[4*p + m] = acc3[4*p + m] + bq[m];
        }
        transition(v3v, g, a4h, a4l);
    };
    auto heads_store = [&](const FragU* a4h, const FragU* a4l, int t_lane, int arow) {
        const f32x4 hb1q0 = *(const f32x4*)&sB[96  + t_lane*16 + 4*g];
        const f32x4 hb1q1 = *(const f32x4*)&sB[96  + t_lane*16 + 8 + 4*g];
        const f32x4 hw2q0 = *(const f32x4*)&sB[224 + t_lane*16 + 4*g];
        const f32x4 hw2q1 = *(const f32x4*)&sB[224 + t_lane*16 + 8 + 4*g];

        float ys = 0.f;
#pragma unroll
        for (int n = 0; n < 4; ++n) {
            f32x16 hacc = zero16();
#pragma unroll
            for (int f2 = 0; f2 < 2; ++f2) {
                FragU WH, WL;
                WH.u4 = wf4[(32 + 4*n + 2*f2) * 64 + l];
                WL.u4 = wf4[(33 + 4*n + 2*f2) * 64 + l];
                hacc = mfma16(WH.v, a4h[f2].v, hacc);
                hacc = mfma16(WL.v, a4h[f2].v, hacc);
                hacc = mfma16(WH.v, a4l[f2].v, hacc);
            }
            const bool sel = ((t_lane >> 1) == n);
            const bool half = (t_lane & 1);
#pragma unroll
            for (int j = 0; j < 8; ++j) {
                const float bb = (j < 4) ? hb1q0[j] : hb1q1[j - 4];
                const float ww = (j < 4) ? hw2q0[j] : hw2q1[j - 4];
                const float c0 = fmaxf(hacc[j]     + bb, 0.f) * ww;
                const float c1 = fmaxf(hacc[8 + j] + bb, 0.f) * ww;
                const float pick = half ? c1 : c0;
                ys += sel ? pick : 0.f;
            }
        }
        const float ytot = ys + __shfl_xor(ys, 32);
        if (g == 0)
            out[arow] = ytot + sB[352 + t_lane];
    };

    // ---------------- pipelined 2-tile schedule ----------------
    const int tb1 = rowbase, tb2 = rowbase + 32;

    stage_x(tb1);
    i32x4 iq1[2]; int t1;
    load_idx(tb1, iq1, t1);

    fence_vm0();                      // xb(t1) + iq1 + t1 ready

    uint4 ehv1[8];
    gather_emb(iq1, ehv1);            // in flight under cont1

    f32x16 acca = zero16(), accb = zero16();
    layer1_cont(acca, accb);

    fence_lgkm0();                    // xb ds_reads retired -> safe to overwrite
    stage_x(tb2);                     // tile-2 staging flies under t1 compute
    i32x4 iq2[2]; int t2;
    load_idx(tb2, iq2, t2);

    layer1_emb(ehv1, acca, accb);     // compiler waits ehv1 here
    FragU a4h[2], a4l[2];
    mid(acca, accb, a4h, a4l);

    uint4 ehv2[8];
    gather_emb(iq2, ehv2);            // in flight under heads1

    heads_store(a4h, a4l, t1, tb1 + lc);

    fence_vm0();                      // xb(t2) ready (ehv2 likely landed too)

    acca = zero16(); accb = zero16();
    layer1_cont(acca, accb);
    layer1_emb(ehv2, acca, accb);
    mid(acca, accb, a4h, a4l);
    heads_store(a4h, a4l, t2, tb2 + lc);
}

} // namespace

extern "C" void kernel_launch(void* const* d_in, const int* in_sizes, int n_in,
                              void* d_out, int out_size, void* d_ws, size_t ws_size,
                              hipStream_t stream)
{
    const float* x_cont = (const float*)d_in[0];
    const int*   x_cate = (const int*)  d_in[1];
    const int*   t      = (const int*)  d_in[2];
    const float* emb    = (const float*)d_in[3];
    const float* W1     = (const float*)d_in[4];
    const float* b1     = (const float*)d_in[5];
    const float* W2     = (const float*)d_in[6];
    const float* b2     = (const float*)d_in[7];
    const float* W3     = (const float*)d_in[8];
    const float* b3     = (const float*)d_in[9];
    const float* HW1    = (const float*)d_in[10];
    const float* Hb1    = (const float*)d_in[11];
    const float* HW2    = (const float*)d_in[12];
    const float* Hb2    = (const float*)d_in[13];
    float* out = (float*)d_out;

    ushort* WF = (ushort*)d_ws;
    ushort* eh = (ushort*)((char*)d_ws + kOffEH);

    hipLaunchKernelGGL(build_wfrags, dim3(12), dim3(256), 0, stream, W1, W2, W3, HW1, WF);
    hipLaunchKernelGGL(build_embhi, dim3((kNCate*kVocab + 255)/256), dim3(256), 0, stream,
                       emb, eh);

    const int grid = kRows / 256;   // 2048 blocks; 4 waves x 2 tiles x 32 rows
    hipLaunchKernelGGL(fused_main, dim3(grid), dim3(256), 0, stream,
                       x_cont, x_cate, t, WF, eh,
                       b1, b2, b3, Hb1, HW2, Hb2, out);
}